// Round 1
// baseline (11340.891 us; speedup 1.0000x reference)
//
#include <hip/hip_runtime.h>
#include <math.h>

#define BATCH   8
#define NPTS    32768
#define FDIM    32
#define NGROUP  1024
#define GSIZE   32
#define FPS_TPB 1024
#define PPT     32      // points per thread in FPS (32*1024 = 32768)
#define KLANE   8       // per-lane candidate list length in KNN

// Exact float32 distance in the reference's association: ((dx^2+dy^2)+dz^2),
// with contraction blocked (__f*_rn never fuse) so bits match the numpy ref.
__device__ __forceinline__ float dist2f(float ax, float ay, float az,
                                        float bx, float by, float bz) {
  float dx = __fsub_rn(ax, bx);
  float dy = __fsub_rn(ay, by);
  float dz = __fsub_rn(az, bz);
  return __fadd_rn(__fadd_rn(__fmul_rn(dx, dx), __fmul_rn(dy, dy)),
                   __fmul_rn(dz, dz));
}

// ---------------------------------------------------------------------------
// Kernel A: farthest point sampling, one block per batch.
// State: x,y,dist in VGPRs (96 regs), z in LDS (128 KB, thread-private slots).
// One barrier per iteration; candidate scratch double-buffered by iteration
// parity so a single barrier is race-free.
// ---------------------------------------------------------------------------
__global__ __launch_bounds__(FPS_TPB, 4) void fps_kernel(
    const float* __restrict__ coord, int* __restrict__ s_idx_out) {
  __shared__ float zbuf[NPTS];        // 128 KB
  __shared__ float redv[2][16];
  __shared__ int   redp[2][16];

  const int b    = blockIdx.x;
  const int tid  = threadIdx.x;
  const int lane = tid & 63;
  const int wid  = tid >> 6;
  const float* __restrict__ c = coord + (size_t)b * NPTS * 3;

  float x[PPT], y[PPT], dist[PPT];

  // Load coords: thread owns points p = i*1024 + tid (coalesced-ish float3).
  #pragma unroll
  for (int i = 0; i < PPT; ++i) {
    int p = i * FPS_TPB + tid;
    float3 v = ((const float3*)c)[p];
    x[i] = v.x; y[i] = v.y; zbuf[p] = v.z;
  }

  if (tid == 0) s_idx_out[b * NGROUP + 0] = 0;

  // Init: distance to point 0, track local argmax (ascending p => ties keep
  // lowest index with strict >).
  float qx = c[0], qy = c[1], qz = c[2];
  float bestv = -1.0f; int bestp = 0;
  #pragma unroll
  for (int i = 0; i < PPT; ++i) {
    int p = i * FPS_TPB + tid;
    float d2 = dist2f(x[i], y[i], zbuf[p], qx, qy, qz);
    dist[i] = d2;
    if (d2 > bestv) { bestv = d2; bestp = p; }
  }

  for (int t = 1; t < NGROUP; ++t) {
    // Wave-level argmax (max value, tie -> min index).
    float v = bestv; int p = bestp;
    #pragma unroll
    for (int m = 1; m < 64; m <<= 1) {
      float ov = __shfl_xor(v, m, 64);
      int   op = __shfl_xor(p, m, 64);
      if (ov > v || (ov == v && op < p)) { v = ov; p = op; }
    }
    if (lane == 0) { redv[t & 1][wid] = v; redp[t & 1][wid] = p; }
    __syncthreads();

    // Every thread redundantly reduces the 16 wave candidates (broadcast reads).
    float gv = redv[t & 1][0]; int gp = redp[t & 1][0];
    #pragma unroll
    for (int w = 1; w < 16; ++w) {
      float wv = redv[t & 1][w]; int wp = redp[t & 1][w];
      if (wv > gv || (wv == gv && wp < gp)) { gv = wv; gp = wp; }
    }
    gp = __builtin_amdgcn_readfirstlane(gp);
    if (tid == 0) s_idx_out[b * NGROUP + t] = gp;

    // Fetch chosen point's coords (uniform address, cached).
    qx = c[gp * 3 + 0]; qy = c[gp * 3 + 1]; qz = c[gp * 3 + 2];

    // Update dists + recompute local argmax.
    bestv = -1.0f; bestp = 0;
    #pragma unroll
    for (int i = 0; i < PPT; ++i) {
      int pp = i * FPS_TPB + tid;
      float d2 = dist2f(x[i], y[i], zbuf[pp], qx, qy, qz);
      float nd = fminf(dist[i], d2);
      dist[i] = nd;
      if (nd > bestv) { bestv = nd; bestp = pp; }
    }
  }
}

// ---------------------------------------------------------------------------
// Kernel B: one wave per sampled point. Brute-force 32-NN (per-lane sorted
// top-8 over its 512 strided points, then 32 wave-argmin extractions),
// then the feature-angle curvature and all 5 outputs.
// ---------------------------------------------------------------------------
__global__ __launch_bounds__(256) void knn_kernel(
    const float* __restrict__ coord, const float* __restrict__ feat,
    const int* __restrict__ labels, const int* __restrict__ s_idx_ws,
    float* __restrict__ out) {
  const int lane = threadIdx.x & 63;
  const int qid  = (blockIdx.x << 2) + (threadIdx.x >> 6);  // 0..8191
  const int b    = qid >> 10;
  const float* __restrict__ c = coord + (size_t)b * NPTS * 3;

  int sp = __builtin_amdgcn_readfirstlane(s_idx_ws[qid]);
  const int gq = b * NPTS + sp;
  const float qx = coord[(size_t)gq * 3 + 0];
  const float qy = coord[(size_t)gq * 3 + 1];
  const float qz = coord[(size_t)gq * 3 + 2];

  // Per-lane ascending top-8 (value, index), static indexing only.
  float lv[KLANE]; int li[KLANE];
  #pragma unroll
  for (int j = 0; j < KLANE; ++j) { lv[j] = 1e30f; li[j] = 0x7fffffff; }

  for (int s = 0; s < NPTS / 64; ++s) {
    int p = (s << 6) + lane;
    float3 v = ((const float3*)c)[p];
    float d2 = dist2f(v.x, v.y, v.z, qx, qy, qz);
    if (d2 < lv[KLANE - 1]) {
      // Branchless unrolled sorted insert; strict < keeps equal-distance
      // earlier (lower) indices first, matching lax.top_k tie order.
      #pragma unroll
      for (int j = KLANE - 1; j >= 1; --j) {
        bool up = d2 < lv[j - 1];
        float nv = up ? lv[j - 1] : ((d2 < lv[j]) ? d2 : lv[j]);
        int   ni = up ? li[j - 1] : ((d2 < lv[j]) ? p  : li[j]);
        lv[j] = nv; li[j] = ni;
      }
      if (d2 < lv[0]) { lv[0] = d2; li[0] = p; }
    }
  }

  // Extract the 32 globally smallest (ascending, tie -> lower index).
  // Round r's winner is neighbor r; lane r keeps it. Round 0 is the query
  // itself (d2 == 0), excluded from the angle mean like angles[:, :, 1:].
  int nbp = 0;
  for (int r = 0; r < GSIZE; ++r) {
    float mv = lv[0]; int mp = li[0];
    #pragma unroll
    for (int m = 1; m < 64; m <<= 1) {
      float ov = __shfl_xor(mv, m, 64);
      int   op = __shfl_xor(mp, m, 64);
      if (ov < mv || (ov == mv && op < mp)) { mv = ov; mp = op; }
    }
    if (lane == r) nbp = mp;
    if (lv[0] == mv && li[0] == mp) {  // unique winner pops its head
      #pragma unroll
      for (int j = 0; j < KLANE - 1; ++j) { lv[j] = lv[j + 1]; li[j] = li[j + 1]; }
      lv[KLANE - 1] = 1e30f; li[KLANE - 1] = 0x7fffffff;
    }
  }

  // Angle for lanes 1..31: theta = 2*atan2(||a*|b| - |a|*b||, ||a*|b| + |a|*b||)
  const float* aRow = feat + (size_t)gq * FDIM;
  float my_a = (lane < FDIM) ? aRow[lane] : 0.0f;

  float ang = 0.0f;
  if (lane >= 1 && lane < GSIZE) {
    const float4* a4 = (const float4*)aRow;
    const float4* b4 = (const float4*)(feat + ((size_t)b * NPTS + nbp) * FDIM);
    float4 av[FDIM / 4], bv[FDIM / 4];
    float aa = 0.0f, bb = 0.0f;
    #pragma unroll
    for (int k = 0; k < FDIM / 4; ++k) {
      av[k] = a4[k]; bv[k] = b4[k];
      aa += av[k].x * av[k].x + av[k].y * av[k].y + av[k].z * av[k].z + av[k].w * av[k].w;
      bb += bv[k].x * bv[k].x + bv[k].y * bv[k].y + bv[k].z * bv[k].z + bv[k].w * bv[k].w;
    }
    float an = sqrtf(aa), bn = sqrtf(bb);
    float num2 = 0.0f, den2 = 0.0f;
    #pragma unroll
    for (int k = 0; k < FDIM / 4; ++k) {
      float n0 = av[k].x * bn - an * bv[k].x, d0 = av[k].x * bn + an * bv[k].x;
      float n1 = av[k].y * bn - an * bv[k].y, d1 = av[k].y * bn + an * bv[k].y;
      float n2 = av[k].z * bn - an * bv[k].z, d2_ = av[k].z * bn + an * bv[k].z;
      float n3 = av[k].w * bn - an * bv[k].w, d3 = av[k].w * bn + an * bv[k].w;
      num2 += n0 * n0 + n1 * n1 + n2 * n2 + n3 * n3;
      den2 += d0 * d0 + d1 * d1 + d2_ * d2_ + d3 * d3;
    }
    ang = 2.0f * atan2f(sqrtf(num2), sqrtf(den2));
  }

  // Wave sum of the 31 angles -> p_curv everywhere.
  float tot = ang;
  #pragma unroll
  for (int m = 1; m < 64; m <<= 1) tot += __shfl_xor(tot, m, 64);
  float p_curv = tot / 31.0f;

  // Outputs (flat concatenation, all as float32).
  float* out_xyz  = out;                              // 8192*3
  float* out_feat = out + (size_t)BATCH * NGROUP * 3; // 8192*33
  float* out_sw   = out_feat + (size_t)BATCH * NGROUP * (FDIM + 1);
  float* out_lab  = out_sw  + (size_t)BATCH * NGROUP;
  float* out_sif  = out_lab + (size_t)BATCH * NGROUP;

  if (lane < FDIM)  out_feat[(size_t)qid * (FDIM + 1) + lane] = my_a;
  if (lane == FDIM) out_feat[(size_t)qid * (FDIM + 1) + FDIM] = p_curv;
  if (lane == 0) {
    out_xyz[(size_t)qid * 3 + 0] = qx;
    out_xyz[(size_t)qid * 3 + 1] = qy;
    out_xyz[(size_t)qid * 3 + 2] = qz;
    out_sw[qid]  = (p_curv > 0.087266f) ? 1.0f : 0.0f;
    out_lab[qid] = (float)labels[gq];
    out_sif[qid] = (float)gq;   // s_idx + b*N
  }
}

extern "C" void kernel_launch(void* const* d_in, const int* in_sizes, int n_in,
                              void* d_out, int out_size, void* d_ws, size_t ws_size,
                              hipStream_t stream) {
  const float* coord  = (const float*)d_in[0];
  const float* feat   = (const float*)d_in[1];
  const int*   labels = (const int*)d_in[2];
  int* s_idx_ws = (int*)d_ws;  // 8*1024 int32

  fps_kernel<<<BATCH, FPS_TPB, 0, stream>>>(coord, s_idx_ws);
  knn_kernel<<<(BATCH * NGROUP) / 4, 256, 0, stream>>>(coord, feat, labels,
                                                       s_idx_ws, (float*)d_out);
}

// Round 2
// 11055.659 us; speedup vs baseline: 1.0258x; 1.0258x over previous
//
#include <hip/hip_runtime.h>
#include <math.h>

#define BATCH   8
#define NPTS    32768
#define FDIM    32
#define NGROUP  1024
#define GSIZE   32
#define FPS_TPB 1024
#define PPT     32      // points per thread in FPS (32*1024 = 32768)
#define KLANE   8       // per-lane candidate list length in KNN

// Exact float32 distance in the reference's association: ((dx^2+dy^2)+dz^2),
// with contraction blocked (__f*_rn never fuse) so bits match the numpy ref.
__device__ __forceinline__ float dist2f(float ax, float ay, float az,
                                        float bx, float by, float bz) {
  float dx = __fsub_rn(ax, bx);
  float dy = __fsub_rn(ay, by);
  float dz = __fsub_rn(az, bz);
  return __fadd_rn(__fadd_rn(__fmul_rn(dx, dx), __fmul_rn(dy, dy)),
                   __fmul_rn(dz, dz));
}

// ---------------------------------------------------------------------------
// Kernel A: farthest point sampling, one block per batch.
// State: x,y,dist in VGPRs (96 regs), z in LDS (128 KB, thread-private slots).
// __launch_bounds__(1024, 1): LDS caps us at 1 block/CU anyway; demand the
// full 128-VGPR budget so the 96-float state does NOT spill (R0's 64-VGPR
// allocation spilled all three arrays to scratch -> 10.8 ms).
// Two barriers/iter: wave-argmax -> wave0 reduces 16 candidates + fetches
// query coords -> float4 LDS broadcast.
// ---------------------------------------------------------------------------
__global__ __launch_bounds__(FPS_TPB, 1) void fps_kernel(
    const float* __restrict__ coord, int* __restrict__ s_idx_out) {
  __shared__ float  zbuf[NPTS];        // 128 KB
  __shared__ float  redv[16];
  __shared__ int    redp[16];
  __shared__ float4 bcastq;            // {qx, qy, qz, unused}

  const int b    = blockIdx.x;
  const int tid  = threadIdx.x;
  const int lane = tid & 63;
  const int wid  = tid >> 6;
  const float* __restrict__ c = coord + (size_t)b * NPTS * 3;

  float x[PPT], y[PPT], dist[PPT];

  // Load coords: thread owns points p = i*1024 + tid.
  #pragma unroll
  for (int i = 0; i < PPT; ++i) {
    int p = i * FPS_TPB + tid;
    float3 v = ((const float3*)c)[p];
    x[i] = v.x; y[i] = v.y; zbuf[p] = v.z;
  }

  if (tid == 0) s_idx_out[b * NGROUP + 0] = 0;

  // Init: distance to point 0, track local argmax (ascending p + strict >
  // keeps the lowest index on ties, matching np.argmax).
  float qx = c[0], qy = c[1], qz = c[2];
  float bestv = -1.0f; int bestp = 0;
  #pragma unroll
  for (int i = 0; i < PPT; ++i) {
    int p = i * FPS_TPB + tid;
    float d2 = dist2f(x[i], y[i], zbuf[p], qx, qy, qz);
    dist[i] = d2;
    if (d2 > bestv) { bestv = d2; bestp = p; }
  }

  for (int t = 1; t < NGROUP; ++t) {
    // Stage 1: wave-level argmax (max value, tie -> min index).
    float v = bestv; int p = bestp;
    #pragma unroll
    for (int m = 1; m < 64; m <<= 1) {
      float ov = __shfl_xor(v, m, 64);
      int   op = __shfl_xor(p, m, 64);
      if (ov > v || (ov == v && op < p)) { v = ov; p = op; }
    }
    if (lane == 0) { redv[wid] = v; redp[wid] = p; }
    __syncthreads();

    // Stage 2: wave 0 reduces the 16 wave candidates, fetches the winner's
    // coords, broadcasts via LDS. (xor-butterfly over lanes 0..15; lanes
    // 16..63 compute garbage harmlessly.)
    if (wid == 0) {
      float gv = redv[lane & 15]; int gp = redp[lane & 15];
      #pragma unroll
      for (int m = 1; m < 16; m <<= 1) {
        float ov = __shfl_xor(gv, m, 64);
        int   op = __shfl_xor(gp, m, 64);
        if (ov > gv || (ov == gv && op < gp)) { gv = ov; gp = op; }
      }
      if (lane == 0) {
        s_idx_out[b * NGROUP + t] = gp;
        float4 q;
        q.x = c[gp * 3 + 0]; q.y = c[gp * 3 + 1]; q.z = c[gp * 3 + 2];
        q.w = 0.0f;
        bcastq = q;
      }
    }
    __syncthreads();

    float4 q = bcastq;
    qx = q.x; qy = q.y; qz = q.z;

    // Update dists + recompute local argmax.
    bestv = -1.0f; bestp = 0;
    #pragma unroll
    for (int i = 0; i < PPT; ++i) {
      int pp = i * FPS_TPB + tid;
      float d2 = dist2f(x[i], y[i], zbuf[pp], qx, qy, qz);
      float nd = fminf(dist[i], d2);
      dist[i] = nd;
      if (nd > bestv) { bestv = nd; bestp = pp; }
    }
  }
}

// ---------------------------------------------------------------------------
// Kernel B: one wave per sampled point. Brute-force 32-NN (per-lane sorted
// top-8 over its 512 strided points, then 32 wave-argmin extractions),
// then the feature-angle curvature and all 5 outputs.
// ---------------------------------------------------------------------------
__global__ __launch_bounds__(256) void knn_kernel(
    const float* __restrict__ coord, const float* __restrict__ feat,
    const int* __restrict__ labels, const int* __restrict__ s_idx_ws,
    float* __restrict__ out) {
  const int lane = threadIdx.x & 63;
  const int qid  = (blockIdx.x << 2) + (threadIdx.x >> 6);  // 0..8191
  const int b    = qid >> 10;
  const float* __restrict__ c = coord + (size_t)b * NPTS * 3;

  int sp = __builtin_amdgcn_readfirstlane(s_idx_ws[qid]);
  const int gq = b * NPTS + sp;
  const float qx = coord[(size_t)gq * 3 + 0];
  const float qy = coord[(size_t)gq * 3 + 1];
  const float qz = coord[(size_t)gq * 3 + 2];

  // Per-lane ascending top-8 (value, index), static indexing only.
  float lv[KLANE]; int li[KLANE];
  #pragma unroll
  for (int j = 0; j < KLANE; ++j) { lv[j] = 1e30f; li[j] = 0x7fffffff; }

  for (int s = 0; s < NPTS / 64; ++s) {
    int p = (s << 6) + lane;
    float3 v = ((const float3*)c)[p];
    float d2 = dist2f(v.x, v.y, v.z, qx, qy, qz);
    if (d2 < lv[KLANE - 1]) {
      // Branchless unrolled sorted insert; strict < keeps equal-distance
      // earlier (lower) indices first, matching lax.top_k tie order.
      #pragma unroll
      for (int j = KLANE - 1; j >= 1; --j) {
        bool up = d2 < lv[j - 1];
        float nv = up ? lv[j - 1] : ((d2 < lv[j]) ? d2 : lv[j]);
        int   ni = up ? li[j - 1] : ((d2 < lv[j]) ? p  : li[j]);
        lv[j] = nv; li[j] = ni;
      }
      if (d2 < lv[0]) { lv[0] = d2; li[0] = p; }
    }
  }

  // Extract the 32 globally smallest (ascending, tie -> lower index).
  // Round r's winner is neighbor r; lane r keeps it. Round 0 is the query
  // itself (d2 == 0), excluded from the angle mean like angles[:, :, 1:].
  int nbp = 0;
  for (int r = 0; r < GSIZE; ++r) {
    float mv = lv[0]; int mp = li[0];
    #pragma unroll
    for (int m = 1; m < 64; m <<= 1) {
      float ov = __shfl_xor(mv, m, 64);
      int   op = __shfl_xor(mp, m, 64);
      if (ov < mv || (ov == mv && op < mp)) { mv = ov; mp = op; }
    }
    if (lane == r) nbp = mp;
    if (lv[0] == mv && li[0] == mp) {  // unique winner pops its head
      #pragma unroll
      for (int j = 0; j < KLANE - 1; ++j) { lv[j] = lv[j + 1]; li[j] = li[j + 1]; }
      lv[KLANE - 1] = 1e30f; li[KLANE - 1] = 0x7fffffff;
    }
  }

  // Angle for lanes 1..31: theta = 2*atan2(||a*|b| - |a|*b||, ||a*|b| + |a|*b||)
  const float* aRow = feat + (size_t)gq * FDIM;
  float my_a = (lane < FDIM) ? aRow[lane] : 0.0f;

  float ang = 0.0f;
  if (lane >= 1 && lane < GSIZE) {
    const float4* a4 = (const float4*)aRow;
    const float4* b4 = (const float4*)(feat + ((size_t)b * NPTS + nbp) * FDIM);
    float4 av[FDIM / 4], bv[FDIM / 4];
    float aa = 0.0f, bb = 0.0f;
    #pragma unroll
    for (int k = 0; k < FDIM / 4; ++k) {
      av[k] = a4[k]; bv[k] = b4[k];
      aa += av[k].x * av[k].x + av[k].y * av[k].y + av[k].z * av[k].z + av[k].w * av[k].w;
      bb += bv[k].x * bv[k].x + bv[k].y * bv[k].y + bv[k].z * bv[k].z + bv[k].w * bv[k].w;
    }
    float an = sqrtf(aa), bn = sqrtf(bb);
    float num2 = 0.0f, den2 = 0.0f;
    #pragma unroll
    for (int k = 0; k < FDIM / 4; ++k) {
      float n0 = av[k].x * bn - an * bv[k].x, d0 = av[k].x * bn + an * bv[k].x;
      float n1 = av[k].y * bn - an * bv[k].y, d1 = av[k].y * bn + an * bv[k].y;
      float n2 = av[k].z * bn - an * bv[k].z, d2_ = av[k].z * bn + an * bv[k].z;
      float n3 = av[k].w * bn - an * bv[k].w, d3 = av[k].w * bn + an * bv[k].w;
      num2 += n0 * n0 + n1 * n1 + n2 * n2 + n3 * n3;
      den2 += d0 * d0 + d1 * d1 + d2_ * d2_ + d3 * d3;
    }
    ang = 2.0f * atan2f(sqrtf(num2), sqrtf(den2));
  }

  // Wave sum of the 31 angles -> p_curv everywhere.
  float tot = ang;
  #pragma unroll
  for (int m = 1; m < 64; m <<= 1) tot += __shfl_xor(tot, m, 64);
  float p_curv = tot / 31.0f;

  // Outputs (flat concatenation, all as float32).
  float* out_xyz  = out;                              // 8192*3
  float* out_feat = out + (size_t)BATCH * NGROUP * 3; // 8192*33
  float* out_sw   = out_feat + (size_t)BATCH * NGROUP * (FDIM + 1);
  float* out_lab  = out_sw  + (size_t)BATCH * NGROUP;
  float* out_sif  = out_lab + (size_t)BATCH * NGROUP;

  if (lane < FDIM)  out_feat[(size_t)qid * (FDIM + 1) + lane] = my_a;
  if (lane == FDIM) out_feat[(size_t)qid * (FDIM + 1) + FDIM] = p_curv;
  if (lane == 0) {
    out_xyz[(size_t)qid * 3 + 0] = qx;
    out_xyz[(size_t)qid * 3 + 1] = qy;
    out_xyz[(size_t)qid * 3 + 2] = qz;
    out_sw[qid]  = (p_curv > 0.087266f) ? 1.0f : 0.0f;
    out_lab[qid] = (float)labels[gq];
    out_sif[qid] = (float)gq;   // s_idx + b*N
  }
}

extern "C" void kernel_launch(void* const* d_in, const int* in_sizes, int n_in,
                              void* d_out, int out_size, void* d_ws, size_t ws_size,
                              hipStream_t stream) {
  const float* coord  = (const float*)d_in[0];
  const float* feat   = (const float*)d_in[1];
  const int*   labels = (const int*)d_in[2];
  int* s_idx_ws = (int*)d_ws;  // 8*1024 int32

  fps_kernel<<<BATCH, FPS_TPB, 0, stream>>>(coord, s_idx_ws);
  knn_kernel<<<(BATCH * NGROUP) / 4, 256, 0, stream>>>(coord, feat, labels,
                                                       s_idx_ws, (float*)d_out);
}

// Round 3
// 11055.499 us; speedup vs baseline: 1.0258x; 1.0000x over previous
//
#include <hip/hip_runtime.h>
#include <math.h>

#define BATCH   8
#define NPTS    32768
#define FDIM    32
#define NGROUP  1024
#define GSIZE   32
#define FPS_TPB 1024
#define PPT     32      // points per thread in FPS (32*1024 = 32768)
#define KLANE   8       // per-lane candidate list length in KNN

// Exact float32 distance in the reference's association: ((dx^2+dy^2)+dz^2),
// with contraction blocked (__f*_rn never fuse) so bits match the numpy ref.
__device__ __forceinline__ float dist2f(float ax, float ay, float az,
                                        float bx, float by, float bz) {
  float dx = __fsub_rn(ax, bx);
  float dy = __fsub_rn(ay, by);
  float dz = __fsub_rn(az, bz);
  return __fadd_rn(__fadd_rn(__fmul_rn(dx, dx), __fmul_rn(dy, dy)),
                   __fmul_rn(dz, dz));
}

// ---------------------------------------------------------------------------
// Kernel A: farthest point sampling, one block per batch.
// State: x,y,dist in VGPRs (96 regs), z in LDS (128 KB, thread-private slots).
// R1 showed __launch_bounds__(1024,1) still allocates only 64 VGPRs ->
// everything spills to scratch (L2) -> 10.5 ms. Force the budget explicitly:
// 16 waves/block = exactly 4 waves/SIMD (LDS caps at 1 block/CU), so
// amdgpu_waves_per_eu(4,4) legalizes 512/4 = 128 VGPRs and tells the
// allocator not to chase higher occupancy.
// ---------------------------------------------------------------------------
__global__
__attribute__((amdgpu_flat_work_group_size(1024, 1024)))
__attribute__((amdgpu_waves_per_eu(4, 4)))
void fps_kernel(const float* __restrict__ coord, int* __restrict__ s_idx_out) {
  __shared__ float  zbuf[NPTS];        // 128 KB
  __shared__ float  redv[16];
  __shared__ int    redp[16];
  __shared__ float4 bcastq;            // {qx, qy, qz, unused}

  const int b    = blockIdx.x;
  const int tid  = threadIdx.x;
  const int lane = tid & 63;
  const int wid  = tid >> 6;
  const float* __restrict__ c = coord + (size_t)b * NPTS * 3;

  float x[PPT], y[PPT], dist[PPT];

  // Load coords: thread owns points p = i*1024 + tid.
  #pragma unroll
  for (int i = 0; i < PPT; ++i) {
    int p = i * FPS_TPB + tid;
    float3 v = ((const float3*)c)[p];
    x[i] = v.x; y[i] = v.y; zbuf[p] = v.z;
  }

  if (tid == 0) s_idx_out[b * NGROUP + 0] = 0;

  // Init: distance to point 0, track local argmax (ascending p + strict >
  // keeps the lowest index on ties, matching np.argmax).
  float qx = c[0], qy = c[1], qz = c[2];
  float bestv = -1.0f; int bestp = 0;
  #pragma unroll
  for (int i = 0; i < PPT; ++i) {
    int p = i * FPS_TPB + tid;
    float d2 = dist2f(x[i], y[i], zbuf[p], qx, qy, qz);
    dist[i] = d2;
    if (d2 > bestv) { bestv = d2; bestp = p; }
  }

  for (int t = 1; t < NGROUP; ++t) {
    // Stage 1: wave-level argmax (max value, tie -> min index).
    float v = bestv; int p = bestp;
    #pragma unroll
    for (int m = 1; m < 64; m <<= 1) {
      float ov = __shfl_xor(v, m, 64);
      int   op = __shfl_xor(p, m, 64);
      if (ov > v || (ov == v && op < p)) { v = ov; p = op; }
    }
    if (lane == 0) { redv[wid] = v; redp[wid] = p; }
    __syncthreads();

    // Stage 2: wave 0 reduces the 16 wave candidates, fetches the winner's
    // coords, broadcasts via LDS. (xor-butterfly over lanes 0..15; lanes
    // 16..63 compute garbage harmlessly.)
    if (wid == 0) {
      float gv = redv[lane & 15]; int gp = redp[lane & 15];
      #pragma unroll
      for (int m = 1; m < 16; m <<= 1) {
        float ov = __shfl_xor(gv, m, 64);
        int   op = __shfl_xor(gp, m, 64);
        if (ov > gv || (ov == gv && op < gp)) { gv = ov; gp = op; }
      }
      if (lane == 0) {
        s_idx_out[b * NGROUP + t] = gp;
        float4 q;
        q.x = c[gp * 3 + 0]; q.y = c[gp * 3 + 1]; q.z = c[gp * 3 + 2];
        q.w = 0.0f;
        bcastq = q;
      }
    }
    __syncthreads();

    float4 q = bcastq;
    qx = q.x; qy = q.y; qz = q.z;

    // Update dists + recompute local argmax.
    bestv = -1.0f; bestp = 0;
    #pragma unroll
    for (int i = 0; i < PPT; ++i) {
      int pp = i * FPS_TPB + tid;
      float d2 = dist2f(x[i], y[i], zbuf[pp], qx, qy, qz);
      float nd = fminf(dist[i], d2);
      dist[i] = nd;
      if (nd > bestv) { bestv = nd; bestp = pp; }
    }
  }
}

// ---------------------------------------------------------------------------
// Kernel B: one wave per sampled point. Brute-force 32-NN (per-lane sorted
// top-8 over its 512 strided points, then 32 wave-argmin extractions),
// then the feature-angle curvature and all 5 outputs.
// ---------------------------------------------------------------------------
__global__ __launch_bounds__(256) void knn_kernel(
    const float* __restrict__ coord, const float* __restrict__ feat,
    const int* __restrict__ labels, const int* __restrict__ s_idx_ws,
    float* __restrict__ out) {
  const int lane = threadIdx.x & 63;
  const int qid  = (blockIdx.x << 2) + (threadIdx.x >> 6);  // 0..8191
  const int b    = qid >> 10;
  const float* __restrict__ c = coord + (size_t)b * NPTS * 3;

  int sp = __builtin_amdgcn_readfirstlane(s_idx_ws[qid]);
  const int gq = b * NPTS + sp;
  const float qx = coord[(size_t)gq * 3 + 0];
  const float qy = coord[(size_t)gq * 3 + 1];
  const float qz = coord[(size_t)gq * 3 + 2];

  // Per-lane ascending top-8 (value, index), static indexing only.
  float lv[KLANE]; int li[KLANE];
  #pragma unroll
  for (int j = 0; j < KLANE; ++j) { lv[j] = 1e30f; li[j] = 0x7fffffff; }

  for (int s = 0; s < NPTS / 64; ++s) {
    int p = (s << 6) + lane;
    float3 v = ((const float3*)c)[p];
    float d2 = dist2f(v.x, v.y, v.z, qx, qy, qz);
    if (d2 < lv[KLANE - 1]) {
      // Branchless unrolled sorted insert; strict < keeps equal-distance
      // earlier (lower) indices first, matching lax.top_k tie order.
      #pragma unroll
      for (int j = KLANE - 1; j >= 1; --j) {
        bool up = d2 < lv[j - 1];
        float nv = up ? lv[j - 1] : ((d2 < lv[j]) ? d2 : lv[j]);
        int   ni = up ? li[j - 1] : ((d2 < lv[j]) ? p  : li[j]);
        lv[j] = nv; li[j] = ni;
      }
      if (d2 < lv[0]) { lv[0] = d2; li[0] = p; }
    }
  }

  // Extract the 32 globally smallest (ascending, tie -> lower index).
  // Round r's winner is neighbor r; lane r keeps it. Round 0 is the query
  // itself (d2 == 0), excluded from the angle mean like angles[:, :, 1:].
  int nbp = 0;
  for (int r = 0; r < GSIZE; ++r) {
    float mv = lv[0]; int mp = li[0];
    #pragma unroll
    for (int m = 1; m < 64; m <<= 1) {
      float ov = __shfl_xor(mv, m, 64);
      int   op = __shfl_xor(mp, m, 64);
      if (ov < mv || (ov == mv && op < mp)) { mv = ov; mp = op; }
    }
    if (lane == r) nbp = mp;
    if (lv[0] == mv && li[0] == mp) {  // unique winner pops its head
      #pragma unroll
      for (int j = 0; j < KLANE - 1; ++j) { lv[j] = lv[j + 1]; li[j] = li[j + 1]; }
      lv[KLANE - 1] = 1e30f; li[KLANE - 1] = 0x7fffffff;
    }
  }

  // Angle for lanes 1..31: theta = 2*atan2(||a*|b| - |a|*b||, ||a*|b| + |a|*b||)
  const float* aRow = feat + (size_t)gq * FDIM;
  float my_a = (lane < FDIM) ? aRow[lane] : 0.0f;

  float ang = 0.0f;
  if (lane >= 1 && lane < GSIZE) {
    const float4* a4 = (const float4*)aRow;
    const float4* b4 = (const float4*)(feat + ((size_t)b * NPTS + nbp) * FDIM);
    float4 av[FDIM / 4], bv[FDIM / 4];
    float aa = 0.0f, bb = 0.0f;
    #pragma unroll
    for (int k = 0; k < FDIM / 4; ++k) {
      av[k] = a4[k]; bv[k] = b4[k];
      aa += av[k].x * av[k].x + av[k].y * av[k].y + av[k].z * av[k].z + av[k].w * av[k].w;
      bb += bv[k].x * bv[k].x + bv[k].y * bv[k].y + bv[k].z * bv[k].z + bv[k].w * bv[k].w;
    }
    float an = sqrtf(aa), bn = sqrtf(bb);
    float num2 = 0.0f, den2 = 0.0f;
    #pragma unroll
    for (int k = 0; k < FDIM / 4; ++k) {
      float n0 = av[k].x * bn - an * bv[k].x, d0 = av[k].x * bn + an * bv[k].x;
      float n1 = av[k].y * bn - an * bv[k].y, d1 = av[k].y * bn + an * bv[k].y;
      float n2 = av[k].z * bn - an * bv[k].z, d2_ = av[k].z * bn + an * bv[k].z;
      float n3 = av[k].w * bn - an * bv[k].w, d3 = av[k].w * bn + an * bv[k].w;
      num2 += n0 * n0 + n1 * n1 + n2 * n2 + n3 * n3;
      den2 += d0 * d0 + d1 * d1 + d2_ * d2_ + d3 * d3;
    }
    ang = 2.0f * atan2f(sqrtf(num2), sqrtf(den2));
  }

  // Wave sum of the 31 angles -> p_curv everywhere.
  float tot = ang;
  #pragma unroll
  for (int m = 1; m < 64; m <<= 1) tot += __shfl_xor(tot, m, 64);
  float p_curv = tot / 31.0f;

  // Outputs (flat concatenation, all as float32).
  float* out_xyz  = out;                              // 8192*3
  float* out_feat = out + (size_t)BATCH * NGROUP * 3; // 8192*33
  float* out_sw   = out_feat + (size_t)BATCH * NGROUP * (FDIM + 1);
  float* out_lab  = out_sw  + (size_t)BATCH * NGROUP;
  float* out_sif  = out_lab + (size_t)BATCH * NGROUP;

  if (lane < FDIM)  out_feat[(size_t)qid * (FDIM + 1) + lane] = my_a;
  if (lane == FDIM) out_feat[(size_t)qid * (FDIM + 1) + FDIM] = p_curv;
  if (lane == 0) {
    out_xyz[(size_t)qid * 3 + 0] = qx;
    out_xyz[(size_t)qid * 3 + 1] = qy;
    out_xyz[(size_t)qid * 3 + 2] = qz;
    out_sw[qid]  = (p_curv > 0.087266f) ? 1.0f : 0.0f;
    out_lab[qid] = (float)labels[gq];
    out_sif[qid] = (float)gq;   // s_idx + b*N
  }
}

extern "C" void kernel_launch(void* const* d_in, const int* in_sizes, int n_in,
                              void* d_out, int out_size, void* d_ws, size_t ws_size,
                              hipStream_t stream) {
  const float* coord  = (const float*)d_in[0];
  const float* feat   = (const float*)d_in[1];
  const int*   labels = (const int*)d_in[2];
  int* s_idx_ws = (int*)d_ws;  // 8*1024 int32

  fps_kernel<<<BATCH, FPS_TPB, 0, stream>>>(coord, s_idx_ws);
  knn_kernel<<<(BATCH * NGROUP) / 4, 256, 0, stream>>>(coord, feat, labels,
                                                       s_idx_ws, (float*)d_out);
}